// Round 6
// baseline (280.958 us; speedup 1.0000x reference)
//
#include <hip/hip_runtime.h>
#include <hip/hip_bf16.h>
#include <math.h>

// Problem constants: B=8, T=1, H=16, DH=256, DMODEL=4096, PAST=4096,
// ROTARY_DIM=64, ROPE_BASE=10000
#define NB 8
#define NH 16
#define DHD 256
#define DM 4096
#define NPAST 4096
#define STOT 4097          // PAST + T
#define NSPLIT 16          // flash-decode splits per (b,h)
#define KPS 256            // NPAST / NSPLIT (past keys per split)

__device__ __forceinline__ float dot4(float4 a, float4 b) {
  return fmaf(a.x, b.x, fmaf(a.y, b.y, fmaf(a.z, b.z, a.w * b.w)));
}

// ---------------- kernel 1: fused QKV GEMV (8 RHS) + RoPE epilogue -----------
__global__ __launch_bounds__(256) void k_qkv(const float* __restrict__ hid,
                                             const float* __restrict__ Wq,
                                             const float* __restrict__ Wk,
                                             const float* __restrict__ Wv,
                                             const int* __restrict__ pos,
                                             float* __restrict__ qb,
                                             float* __restrict__ kb,
                                             float* __restrict__ vb) {
  const int lane = threadIdx.x & 63;
  const int wid  = threadIdx.x >> 6;
  const int task = blockIdx.x * 4 + wid;      // 0..3071
  const int mat  = task >> 10;                // 0=q 1=k 2=v (wave-uniform)
  const int r    = (task & 1023) << 2;        // row base, multiple of 4
  const float* W = (mat == 0) ? Wq : ((mat == 1) ? Wk : Wv);
  float* out     = (mat == 0) ? qb : ((mat == 1) ? kb : vb);
  const float4* W4 = (const float4*)(W + (size_t)r * DM);
  const float4* h4 = (const float4*)hid;

  float a0[8], a1[8], a2[8], a3[8];
#pragma unroll
  for (int b = 0; b < 8; ++b) a0[b] = a1[b] = a2[b] = a3[b] = 0.f;

  for (int it = 0; it < 16; ++it) {
    const int c4 = it * 64 + lane;            // coalesced float4 column
    const float4 w0 = W4[c4];
    const float4 w1 = W4[1024 + c4];
    const float4 w2 = W4[2048 + c4];
    const float4 w3 = W4[3072 + c4];
#pragma unroll
    for (int b = 0; b < 8; ++b) {
      const float4 hv = h4[b * 1024 + c4];
      a0[b] += dot4(w0, hv);
      a1[b] += dot4(w1, hv);
      a2[b] += dot4(w2, hv);
      a3[b] += dot4(w3, hv);
    }
  }

#pragma unroll
  for (int off = 32; off > 0; off >>= 1) {
#pragma unroll
    for (int b = 0; b < 8; ++b) {
      a0[b] += __shfl_xor(a0[b], off, 64);
      a1[b] += __shfl_xor(a1[b], off, 64);
      a2[b] += __shfl_xor(a2[b], off, 64);
      a3[b] += __shfl_xor(a3[b], off, 64);
    }
  }

  // RoPE epilogue (q,k only; first 64 dims of each head)
  const int d = r & 255;                       // dim within head
  const bool rope = (mat < 2) && (d < 64);
  float s0v = 0.f, c0v = 1.f, s1v = 0.f, c1v = 1.f;
  if (rope) {
    const int i0 = d >> 1;                     // pair index (wave-uniform)
    const float inv0 = (float)pow(10000.0, -(double)i0 / 32.0);
    const float inv1 = (float)pow(10000.0, -(double)(i0 + 1) / 32.0);
    const float p = (float)pos[lane & 7];
    s0v = sinf(p * inv0); c0v = cosf(p * inv0);
    s1v = sinf(p * inv1); c1v = cosf(p * inv1);
  }
#pragma unroll
  for (int b = 0; b < 8; ++b) {
    if (lane == b) {
      float x0 = a0[b], x1 = a1[b], x2 = a2[b], x3 = a3[b];
      if (rope) {
        float t0 = x0 * c0v - x1 * s0v; x1 = x1 * c0v + x0 * s0v; x0 = t0;
        float t2 = x2 * c1v - x3 * s1v; x3 = x3 * c1v + x2 * s1v; x2 = t2;
      }
      out[b * DM + r + 0] = x0;
      out[b * DM + r + 1] = x1;
      out[b * DM + r + 2] = x2;
      out[b * DM + r + 3] = x3;
    }
  }
}

// ---------------- kernel 2: flash-decode attention ---------------------------
// NSPLIT=16 -> 2048 blocks (8 blocks/CU, 32 waves/CU = occupancy cap), each
// streams a contiguous 256-key window of K and V. Branch-free hot loop with
// 1-deep register prefetch; new-token key handled by split 15 / wave 0.
__global__ __launch_bounds__(256) void k_attn(const float* __restrict__ qb,
                                              const float* __restrict__ kb,
                                              const float* __restrict__ vb,
                                              const float* __restrict__ Kp,
                                              const float* __restrict__ Vp,
                                              const float* __restrict__ mask,
                                              float* __restrict__ pm,
                                              float* __restrict__ pl,
                                              float* __restrict__ pc) {
  const int blk   = blockIdx.x;        // 0..2047
  const int bh    = blk >> 4;
  const int split = blk & 15;
  const int b     = bh >> 4;
  const int lane  = threadIdx.x & 63;
  const int wid   = threadIdx.x >> 6;
  const int start = split * KPS;
  const int end   = start + KPS;       // past keys only (<= NPAST)

  const float4* K4 = (const float4*)Kp + (size_t)bh * NPAST * 64;
  const float4* V4 = (const float4*)Vp + (size_t)bh * NPAST * 64;
  const float4 qv = ((const float4*)qb)[bh * 64 + lane];
  const float* mrow = mask + b * STOT;

  float m = -3.0e38f, l = 0.f;
  float4 ctx = make_float4(0.f, 0.f, 0.f, 0.f);

  int j = start + wid;
  float4 kk = K4[(size_t)j * 64 + lane];
  float4 vv = V4[(size_t)j * 64 + lane];
  float  mk = mrow[j];

  while (j < end) {
    const int jn = j + 4;
    float4 kk2, vv2;
    float  mk2;
    if (jn < end) {                          // wave-uniform; prefetch next
      kk2 = K4[(size_t)jn * 64 + lane];
      vv2 = V4[(size_t)jn * 64 + lane];
      mk2 = mrow[jn];
    }
    float s = dot4(kk, qv);
#pragma unroll
    for (int off = 32; off > 0; off >>= 1) s += __shfl_xor(s, off, 64);
    s = s * 0.0625f + mk;                    // scale = 1/sqrt(256)
    const float mn = fmaxf(m, s);
    const float corr = __expf(m - mn);
    const float p = __expf(s - mn);
    l = l * corr + p;
    ctx.x = fmaf(ctx.x, corr, p * vv.x);
    ctx.y = fmaf(ctx.y, corr, p * vv.y);
    ctx.z = fmaf(ctx.z, corr, p * vv.z);
    ctx.w = fmaf(ctx.w, corr, p * vv.w);
    m = mn;
    j = jn; kk = kk2; vv = vv2; mk = mk2;
  }

  // new token's key (index NPAST): handled once, by last split / wave 0
  if (split == NSPLIT - 1 && wid == 0) {
    const float4 kn = ((const float4*)kb)[bh * 64 + lane];
    const float4 vn = ((const float4*)vb)[bh * 64 + lane];
    float s = dot4(kn, qv);
#pragma unroll
    for (int off = 32; off > 0; off >>= 1) s += __shfl_xor(s, off, 64);
    s = s * 0.0625f + mrow[NPAST];
    const float mn = fmaxf(m, s);
    const float corr = __expf(m - mn);
    const float p = __expf(s - mn);
    l = l * corr + p;
    ctx.x = fmaf(ctx.x, corr, p * vn.x);
    ctx.y = fmaf(ctx.y, corr, p * vn.y);
    ctx.z = fmaf(ctx.z, corr, p * vn.z);
    ctx.w = fmaf(ctx.w, corr, p * vn.w);
    m = mn;
  }

  // combine the block's 4 waves
  __shared__ float sm[4], sl[4];
  __shared__ float4 sctx[4][64];
  if (lane == 0) { sm[wid] = m; sl[wid] = l; }
  sctx[wid][lane] = ctx;
  __syncthreads();

  const float M = fmaxf(fmaxf(sm[0], sm[1]), fmaxf(sm[2], sm[3]));
  const int e = threadIdx.x;                  // 0..255
  const float* sc = (const float*)sctx;       // [4][256]
  float accv = 0.f;
#pragma unroll
  for (int w = 0; w < 4; ++w) accv += sc[w * 256 + e] * __expf(sm[w] - M);
  pc[(size_t)blk * 256 + e] = accv;
  if (threadIdx.x == 0) {
    float L = 0.f;
#pragma unroll
    for (int w = 0; w < 4; ++w) L += sl[w] * __expf(sm[w] - M);
    pm[blk] = M;
    pl[blk] = L;
  }
}

// ---------------- kernel 3: combine splits -> ctx_full ------------------------
__global__ __launch_bounds__(256) void k_comb(const float* __restrict__ pm,
                                              const float* __restrict__ pl,
                                              const float* __restrict__ pc,
                                              float* __restrict__ ctxf) {
  const int bh = blockIdx.x;
  const int e  = threadIdx.x;
  float M = -3.0e38f;
  for (int s = 0; s < NSPLIT; ++s) M = fmaxf(M, pm[bh * NSPLIT + s]);
  float L = 0.f, acc = 0.f;
  for (int s = 0; s < NSPLIT; ++s) {
    const float c = __expf(pm[bh * NSPLIT + s] - M);
    L   += pl[bh * NSPLIT + s] * c;
    acc += pc[((size_t)bh * NSPLIT + s) * 256 + e] * c;
  }
  ctxf[bh * 256 + e] = acc / L;   // [b][h*256+e] layout == transpose+reshape
}

// ---------------- kernel 4: output projection GEMV, 2 rows/wave --------------
__global__ __launch_bounds__(256) void k_out(const float* __restrict__ ctxf,
                                             const float* __restrict__ Wo,
                                             float* __restrict__ out) {
  const int lane = threadIdx.x & 63;
  const int wid  = threadIdx.x >> 6;
  const int task = blockIdx.x * 4 + wid;      // 0..2047
  const int r    = task << 1;                 // 2 rows per wave
  const float4* W4 = (const float4*)(Wo + (size_t)r * DM);
  const float4* x4 = (const float4*)ctxf;

  float a0[8], a1[8];
#pragma unroll
  for (int b = 0; b < 8; ++b) a0[b] = a1[b] = 0.f;

  for (int it = 0; it < 16; ++it) {
    const int c4 = it * 64 + lane;
    const float4 w0 = W4[c4];
    const float4 w1 = W4[1024 + c4];
#pragma unroll
    for (int b = 0; b < 8; ++b) {
      const float4 hv = x4[b * 1024 + c4];
      a0[b] += dot4(w0, hv);
      a1[b] += dot4(w1, hv);
    }
  }
#pragma unroll
  for (int off = 32; off > 0; off >>= 1) {
#pragma unroll
    for (int b = 0; b < 8; ++b) {
      a0[b] += __shfl_xor(a0[b], off, 64);
      a1[b] += __shfl_xor(a1[b], off, 64);
    }
  }
#pragma unroll
  for (int b = 0; b < 8; ++b) {
    if (lane == b) {
      out[b * DM + r + 0] = a0[b];
      out[b * DM + r + 1] = a1[b];
    }
  }
}

extern "C" void kernel_launch(void* const* d_in, const int* in_sizes, int n_in,
                              void* d_out, int out_size, void* d_ws, size_t ws_size,
                              hipStream_t stream) {
  const float* hid  = (const float*)d_in[0];   // [8,1,4096]
  const float* Kp   = (const float*)d_in[1];   // [8,16,4096,256]
  const float* Vp   = (const float*)d_in[2];   // [8,16,4096,256]
  const float* mask = (const float*)d_in[3];   // [8,1,1,4097]
  const int*   pos  = (const int*)d_in[4];     // [8,1] (int32 on device)
  const float* Wq   = (const float*)d_in[5];   // [4096,4096]
  const float* Wk   = (const float*)d_in[6];
  const float* Wv   = (const float*)d_in[7];
  const float* Wo   = (const float*)d_in[8];

  float* ws   = (float*)d_ws;
  float* qb   = ws;                 // 32768  (B*DM)
  float* kb   = ws + 32768;         // 32768
  float* vb   = ws + 65536;         // 32768
  float* ctxf = ws + 98304;         // 32768
  float* pm   = ws + 131072;        // 2048   (B*H*NSPLIT)
  float* pl   = ws + 133120;        // 2048
  float* pc   = ws + 135168;        // 524288 (B*H*NSPLIT*256)
                                    // total ~2.6 MB

  k_qkv <<<768, 256, 0, stream>>>(hid, Wq, Wk, Wv, pos, qb, kb, vb);
  k_attn<<<NB * NH * NSPLIT, 256, 0, stream>>>(qb, kb, vb, Kp, Vp, mask, pm, pl, pc);
  k_comb<<<NB * NH, 256, 0, stream>>>(pm, pl, pc, ctxf);
  k_out <<<512, 256, 0, stream>>>(ctxf, Wo, (float*)d_out);
}

// Round 7
// 273.341 us; speedup vs baseline: 1.0279x; 1.0279x over previous
//
#include <hip/hip_runtime.h>
#include <hip/hip_bf16.h>
#include <math.h>

// Problem constants: B=8, T=1, H=16, DH=256, DMODEL=4096, PAST=4096,
// ROTARY_DIM=64, ROPE_BASE=10000
#define NB 8
#define NH 16
#define DHD 256
#define DM 4096
#define NPAST 4096
#define STOT 4097          // PAST + T
#define NSPLIT 8           // flash-decode splits per (b,h)  (round-5 optimum)
#define KPS 512            // NPAST / NSPLIT (past keys per split)

__device__ __forceinline__ float dot4(float4 a, float4 b) {
  return fmaf(a.x, b.x, fmaf(a.y, b.y, fmaf(a.z, b.z, a.w * b.w)));
}

// ---------------- kernel 1: fused QKV GEMV (8 RHS) + RoPE epilogue -----------
__global__ __launch_bounds__(256) void k_qkv(const float* __restrict__ hid,
                                             const float* __restrict__ Wq,
                                             const float* __restrict__ Wk,
                                             const float* __restrict__ Wv,
                                             const int* __restrict__ pos,
                                             float* __restrict__ qb,
                                             float* __restrict__ kb,
                                             float* __restrict__ vb) {
  const int lane = threadIdx.x & 63;
  const int wid  = threadIdx.x >> 6;
  const int task = blockIdx.x * 4 + wid;      // 0..3071
  const int mat  = task >> 10;                // 0=q 1=k 2=v (wave-uniform)
  const int r    = (task & 1023) << 2;        // row base, multiple of 4
  const float* W = (mat == 0) ? Wq : ((mat == 1) ? Wk : Wv);
  float* out     = (mat == 0) ? qb : ((mat == 1) ? kb : vb);
  const float4* W4 = (const float4*)(W + (size_t)r * DM);
  const float4* h4 = (const float4*)hid;

  float a0[8], a1[8], a2[8], a3[8];
#pragma unroll
  for (int b = 0; b < 8; ++b) a0[b] = a1[b] = a2[b] = a3[b] = 0.f;

  for (int it = 0; it < 16; ++it) {
    const int c4 = it * 64 + lane;            // coalesced float4 column
    const float4 w0 = W4[c4];
    const float4 w1 = W4[1024 + c4];
    const float4 w2 = W4[2048 + c4];
    const float4 w3 = W4[3072 + c4];
#pragma unroll
    for (int b = 0; b < 8; ++b) {
      const float4 hv = h4[b * 1024 + c4];
      a0[b] += dot4(w0, hv);
      a1[b] += dot4(w1, hv);
      a2[b] += dot4(w2, hv);
      a3[b] += dot4(w3, hv);
    }
  }

#pragma unroll
  for (int off = 32; off > 0; off >>= 1) {
#pragma unroll
    for (int b = 0; b < 8; ++b) {
      a0[b] += __shfl_xor(a0[b], off, 64);
      a1[b] += __shfl_xor(a1[b], off, 64);
      a2[b] += __shfl_xor(a2[b], off, 64);
      a3[b] += __shfl_xor(a3[b], off, 64);
    }
  }

  // RoPE epilogue (q,k only; first 64 dims of each head)
  const int d = r & 255;                       // dim within head
  const bool rope = (mat < 2) && (d < 64);
  float s0v = 0.f, c0v = 1.f, s1v = 0.f, c1v = 1.f;
  if (rope) {
    const int i0 = d >> 1;                     // pair index (wave-uniform)
    const float inv0 = (float)pow(10000.0, -(double)i0 / 32.0);
    const float inv1 = (float)pow(10000.0, -(double)(i0 + 1) / 32.0);
    const float p = (float)pos[lane & 7];
    s0v = sinf(p * inv0); c0v = cosf(p * inv0);
    s1v = sinf(p * inv1); c1v = cosf(p * inv1);
  }
#pragma unroll
  for (int b = 0; b < 8; ++b) {
    if (lane == b) {
      float x0 = a0[b], x1 = a1[b], x2 = a2[b], x3 = a3[b];
      if (rope) {
        float t0 = x0 * c0v - x1 * s0v; x1 = x1 * c0v + x0 * s0v; x0 = t0;
        float t2 = x2 * c1v - x3 * s1v; x3 = x3 * c1v + x2 * s1v; x2 = t2;
      }
      out[b * DM + r + 0] = x0;
      out[b * DM + r + 1] = x1;
      out[b * DM + r + 2] = x2;
      out[b * DM + r + 3] = x3;
    }
  }
}

// ---------------- kernel 2: flash-decode attention ---------------------------
// NSPLIT=8 -> 1024 blocks, each streams a contiguous 512-key window of K and V
// (round-5 stream layout). Each wave processes 2 keys/iter (j, j+4) with a
// full-round register prefetch (4 KB in flight/wave) and interleaved
// shuffle-reduce chains. Update order per wave matches round 5 exactly.
__global__ __launch_bounds__(256) void k_attn(const float* __restrict__ qb,
                                              const float* __restrict__ kb,
                                              const float* __restrict__ vb,
                                              const float* __restrict__ Kp,
                                              const float* __restrict__ Vp,
                                              const float* __restrict__ mask,
                                              float* __restrict__ pm,
                                              float* __restrict__ pl,
                                              float* __restrict__ pc) {
  const int blk   = blockIdx.x;        // 0..1023
  const int bh    = blk >> 3;
  const int split = blk & 7;
  const int b     = bh >> 4;
  const int lane  = threadIdx.x & 63;
  const int wid   = threadIdx.x >> 6;
  const int start = split * KPS;
  const int end   = start + KPS;       // past keys only (<= NPAST)

  const float4* K4 = (const float4*)Kp + (size_t)bh * NPAST * 64;
  const float4* V4 = (const float4*)Vp + (size_t)bh * NPAST * 64;
  const float4 qv = ((const float4*)qb)[bh * 64 + lane];
  const float* mrow = mask + b * STOT;

  float m = -3.0e38f, l = 0.f;
  float4 ctx = make_float4(0.f, 0.f, 0.f, 0.f);

  int j = start + wid;
  // preload round 0: keys j and j+4
  float4 kk0 = K4[(size_t)j * 64 + lane];
  float4 vv0 = V4[(size_t)j * 64 + lane];
  float4 kk1 = K4[(size_t)(j + 4) * 64 + lane];
  float4 vv1 = V4[(size_t)(j + 4) * 64 + lane];
  float  mk0 = mrow[j];
  float  mk1 = mrow[j + 4];

  while (j < end) {
    const int jn = j + 8;
    float4 kk0n, vv0n, kk1n, vv1n;
    float  mk0n, mk1n;
    if (jn < end) {                          // wave-uniform; prefetch next round
      kk0n = K4[(size_t)jn * 64 + lane];
      vv0n = V4[(size_t)jn * 64 + lane];
      kk1n = K4[(size_t)(jn + 4) * 64 + lane];
      vv1n = V4[(size_t)(jn + 4) * 64 + lane];
      mk0n = mrow[jn];
      mk1n = mrow[jn + 4];
    }
    float s0 = dot4(kk0, qv);
    float s1 = dot4(kk1, qv);
#pragma unroll
    for (int off = 32; off > 0; off >>= 1) {   // two interleaved chains
      s0 += __shfl_xor(s0, off, 64);
      s1 += __shfl_xor(s1, off, 64);
    }
    s0 = s0 * 0.0625f + mk0;                   // scale = 1/sqrt(256)
    s1 = s1 * 0.0625f + mk1;

    {
      const float mn = fmaxf(m, s0);
      const float corr = __expf(m - mn);
      const float p = __expf(s0 - mn);
      l = l * corr + p;
      ctx.x = fmaf(ctx.x, corr, p * vv0.x);
      ctx.y = fmaf(ctx.y, corr, p * vv0.y);
      ctx.z = fmaf(ctx.z, corr, p * vv0.z);
      ctx.w = fmaf(ctx.w, corr, p * vv0.w);
      m = mn;
    }
    {
      const float mn = fmaxf(m, s1);
      const float corr = __expf(m - mn);
      const float p = __expf(s1 - mn);
      l = l * corr + p;
      ctx.x = fmaf(ctx.x, corr, p * vv1.x);
      ctx.y = fmaf(ctx.y, corr, p * vv1.y);
      ctx.z = fmaf(ctx.z, corr, p * vv1.z);
      ctx.w = fmaf(ctx.w, corr, p * vv1.w);
      m = mn;
    }
    j = jn;
    kk0 = kk0n; vv0 = vv0n; mk0 = mk0n;
    kk1 = kk1n; vv1 = vv1n; mk1 = mk1n;
  }

  // new token's key (index NPAST): handled once, by last split / wave 0
  if (split == NSPLIT - 1 && wid == 0) {
    const float4 kn = ((const float4*)kb)[bh * 64 + lane];
    const float4 vn = ((const float4*)vb)[bh * 64 + lane];
    float s = dot4(kn, qv);
#pragma unroll
    for (int off = 32; off > 0; off >>= 1) s += __shfl_xor(s, off, 64);
    s = s * 0.0625f + mrow[NPAST];
    const float mn = fmaxf(m, s);
    const float corr = __expf(m - mn);
    const float p = __expf(s - mn);
    l = l * corr + p;
    ctx.x = fmaf(ctx.x, corr, p * vn.x);
    ctx.y = fmaf(ctx.y, corr, p * vn.y);
    ctx.z = fmaf(ctx.z, corr, p * vn.z);
    ctx.w = fmaf(ctx.w, corr, p * vn.w);
    m = mn;
  }

  // combine the block's 4 waves
  __shared__ float sm[4], sl[4];
  __shared__ float4 sctx[4][64];
  if (lane == 0) { sm[wid] = m; sl[wid] = l; }
  sctx[wid][lane] = ctx;
  __syncthreads();

  const float M = fmaxf(fmaxf(sm[0], sm[1]), fmaxf(sm[2], sm[3]));
  const int e = threadIdx.x;                  // 0..255
  const float* sc = (const float*)sctx;       // [4][256]
  float accv = 0.f;
#pragma unroll
  for (int w = 0; w < 4; ++w) accv += sc[w * 256 + e] * __expf(sm[w] - M);
  pc[(size_t)blk * 256 + e] = accv;
  if (threadIdx.x == 0) {
    float L = 0.f;
#pragma unroll
    for (int w = 0; w < 4; ++w) L += sl[w] * __expf(sm[w] - M);
    pm[blk] = M;
    pl[blk] = L;
  }
}

// ---------------- kernel 3: combine splits -> ctx_full ------------------------
__global__ __launch_bounds__(256) void k_comb(const float* __restrict__ pm,
                                              const float* __restrict__ pl,
                                              const float* __restrict__ pc,
                                              float* __restrict__ ctxf) {
  const int bh = blockIdx.x;
  const int e  = threadIdx.x;
  float M = -3.0e38f;
  for (int s = 0; s < NSPLIT; ++s) M = fmaxf(M, pm[bh * NSPLIT + s]);
  float L = 0.f, acc = 0.f;
  for (int s = 0; s < NSPLIT; ++s) {
    const float c = __expf(pm[bh * NSPLIT + s] - M);
    L   += pl[bh * NSPLIT + s] * c;
    acc += pc[((size_t)bh * NSPLIT + s) * 256 + e] * c;
  }
  ctxf[bh * 256 + e] = acc / L;   // [b][h*256+e] layout == transpose+reshape
}

// ---------------- kernel 4: output projection GEMV, 2 rows/wave --------------
__global__ __launch_bounds__(256) void k_out(const float* __restrict__ ctxf,
                                             const float* __restrict__ Wo,
                                             float* __restrict__ out) {
  const int lane = threadIdx.x & 63;
  const int wid  = threadIdx.x >> 6;
  const int task = blockIdx.x * 4 + wid;      // 0..2047
  const int r    = task << 1;                 // 2 rows per wave
  const float4* W4 = (const float4*)(Wo + (size_t)r * DM);
  const float4* x4 = (const float4*)ctxf;

  float a0[8], a1[8];
#pragma unroll
  for (int b = 0; b < 8; ++b) a0[b] = a1[b] = 0.f;

  for (int it = 0; it < 16; ++it) {
    const int c4 = it * 64 + lane;
    const float4 w0 = W4[c4];
    const float4 w1 = W4[1024 + c4];
#pragma unroll
    for (int b = 0; b < 8; ++b) {
      const float4 hv = x4[b * 1024 + c4];
      a0[b] += dot4(w0, hv);
      a1[b] += dot4(w1, hv);
    }
  }
#pragma unroll
  for (int off = 32; off > 0; off >>= 1) {
#pragma unroll
    for (int b = 0; b < 8; ++b) {
      a0[b] += __shfl_xor(a0[b], off, 64);
      a1[b] += __shfl_xor(a1[b], off, 64);
    }
  }
#pragma unroll
  for (int b = 0; b < 8; ++b) {
    if (lane == b) {
      out[b * DM + r + 0] = a0[b];
      out[b * DM + r + 1] = a1[b];
    }
  }
}

extern "C" void kernel_launch(void* const* d_in, const int* in_sizes, int n_in,
                              void* d_out, int out_size, void* d_ws, size_t ws_size,
                              hipStream_t stream) {
  const float* hid  = (const float*)d_in[0];   // [8,1,4096]
  const float* Kp   = (const float*)d_in[1];   // [8,16,4096,256]
  const float* Vp   = (const float*)d_in[2];   // [8,16,4096,256]
  const float* mask = (const float*)d_in[3];   // [8,1,1,4097]
  const int*   pos  = (const int*)d_in[4];     // [8,1] (int32 on device)
  const float* Wq   = (const float*)d_in[5];   // [4096,4096]
  const float* Wk   = (const float*)d_in[6];
  const float* Wv   = (const float*)d_in[7];
  const float* Wo   = (const float*)d_in[8];

  float* ws   = (float*)d_ws;
  float* qb   = ws;                 // 32768  (B*DM)
  float* kb   = ws + 32768;         // 32768
  float* vb   = ws + 65536;         // 32768
  float* ctxf = ws + 98304;         // 32768
  float* pm   = ws + 131072;        // 1024   (B*H*NSPLIT)
  float* pl   = ws + 135168;        // 1024
  float* pc   = ws + 139264;        // 262144 (B*H*NSPLIT*256)

  k_qkv <<<768, 256, 0, stream>>>(hid, Wq, Wk, Wv, pos, qb, kb, vb);
  k_attn<<<NB * NH * NSPLIT, 256, 0, stream>>>(qb, kb, vb, Kp, Vp, mask, pm, pl, pc);
  k_comb<<<NB * NH, 256, 0, stream>>>(pm, pl, pc, ctxf);
  k_out <<<512, 256, 0, stream>>>(ctxf, Wo, (float*)d_out);
}

// Round 8
// 237.740 us; speedup vs baseline: 1.1818x; 1.1497x over previous
//
#include <hip/hip_runtime.h>
#include <hip/hip_bf16.h>
#include <math.h>

// Problem constants: B=8, T=1, H=16, DH=256, DMODEL=4096, PAST=4096,
// ROTARY_DIM=64, ROPE_BASE=10000
#define NB 8
#define NH 16
#define DHD 256
#define DM 4096
#define NPAST 4096
#define STOT 4097          // PAST + T
#define NSPLIT 8           // flash-decode splits per (b,h)  (round-5 optimum)
#define KPS 512            // NPAST / NSPLIT (past keys per split)

typedef float f32x4 __attribute__((ext_vector_type(4)));

__device__ __forceinline__ float dot4(float4 a, float4 b) {
  return fmaf(a.x, b.x, fmaf(a.y, b.y, fmaf(a.z, b.z, a.w * b.w)));
}
__device__ __forceinline__ float dot4v(f32x4 a, float4 b) {
  return fmaf(a.x, b.x, fmaf(a.y, b.y, fmaf(a.z, b.z, a.w * b.w)));
}

// ---------------- kernel 1: fused QKV GEMV (8 RHS) + RoPE epilogue -----------
__global__ __launch_bounds__(256) void k_qkv(const float* __restrict__ hid,
                                             const float* __restrict__ Wq,
                                             const float* __restrict__ Wk,
                                             const float* __restrict__ Wv,
                                             const int* __restrict__ pos,
                                             float* __restrict__ qb,
                                             float* __restrict__ kb,
                                             float* __restrict__ vb) {
  const int lane = threadIdx.x & 63;
  const int wid  = threadIdx.x >> 6;
  const int task = blockIdx.x * 4 + wid;      // 0..3071
  const int mat  = task >> 10;                // 0=q 1=k 2=v (wave-uniform)
  const int r    = (task & 1023) << 2;        // row base, multiple of 4
  const float* W = (mat == 0) ? Wq : ((mat == 1) ? Wk : Wv);
  float* out     = (mat == 0) ? qb : ((mat == 1) ? kb : vb);
  const float4* W4 = (const float4*)(W + (size_t)r * DM);
  const float4* h4 = (const float4*)hid;

  float a0[8], a1[8], a2[8], a3[8];
#pragma unroll
  for (int b = 0; b < 8; ++b) a0[b] = a1[b] = a2[b] = a3[b] = 0.f;

  for (int it = 0; it < 16; ++it) {
    const int c4 = it * 64 + lane;            // coalesced float4 column
    const float4 w0 = W4[c4];
    const float4 w1 = W4[1024 + c4];
    const float4 w2 = W4[2048 + c4];
    const float4 w3 = W4[3072 + c4];
#pragma unroll
    for (int b = 0; b < 8; ++b) {
      const float4 hv = h4[b * 1024 + c4];
      a0[b] += dot4(w0, hv);
      a1[b] += dot4(w1, hv);
      a2[b] += dot4(w2, hv);
      a3[b] += dot4(w3, hv);
    }
  }

#pragma unroll
  for (int off = 32; off > 0; off >>= 1) {
#pragma unroll
    for (int b = 0; b < 8; ++b) {
      a0[b] += __shfl_xor(a0[b], off, 64);
      a1[b] += __shfl_xor(a1[b], off, 64);
      a2[b] += __shfl_xor(a2[b], off, 64);
      a3[b] += __shfl_xor(a3[b], off, 64);
    }
  }

  // RoPE epilogue (q,k only; first 64 dims of each head)
  const int d = r & 255;                       // dim within head
  const bool rope = (mat < 2) && (d < 64);
  float s0v = 0.f, c0v = 1.f, s1v = 0.f, c1v = 1.f;
  if (rope) {
    const int i0 = d >> 1;                     // pair index (wave-uniform)
    const float inv0 = (float)pow(10000.0, -(double)i0 / 32.0);
    const float inv1 = (float)pow(10000.0, -(double)(i0 + 1) / 32.0);
    const float p = (float)pos[lane & 7];
    s0v = sinf(p * inv0); c0v = cosf(p * inv0);
    s1v = sinf(p * inv1); c1v = cosf(p * inv1);
  }
#pragma unroll
  for (int b = 0; b < 8; ++b) {
    if (lane == b) {
      float x0 = a0[b], x1 = a1[b], x2 = a2[b], x3 = a3[b];
      if (rope) {
        float t0 = x0 * c0v - x1 * s0v; x1 = x1 * c0v + x0 * s0v; x0 = t0;
        float t2 = x2 * c1v - x3 * s1v; x3 = x3 * c1v + x2 * s1v; x2 = t2;
      }
      out[b * DM + r + 0] = x0;
      out[b * DM + r + 1] = x1;
      out[b * DM + r + 2] = x2;
      out[b * DM + r + 3] = x3;
    }
  }
}

// ---------------- kernel 2: flash-decode attention ---------------------------
// Round-5 structure (NSPLIT=8, 1024 blocks, contiguous 512-key windows,
// 1-deep register prefetch) + NON-TEMPORAL K/V loads (stream bypasses L2
// allocation; bytes are touched exactly once).
__global__ __launch_bounds__(256) void k_attn(const float* __restrict__ qb,
                                              const float* __restrict__ kb,
                                              const float* __restrict__ vb,
                                              const float* __restrict__ Kp,
                                              const float* __restrict__ Vp,
                                              const float* __restrict__ mask,
                                              float* __restrict__ pm,
                                              float* __restrict__ pl,
                                              float* __restrict__ pc) {
  const int blk   = blockIdx.x;        // 0..1023
  const int bh    = blk >> 3;
  const int split = blk & 7;
  const int b     = bh >> 4;
  const int lane  = threadIdx.x & 63;
  const int wid   = threadIdx.x >> 6;
  const int start = split * KPS;
  const int end   = start + KPS;       // past keys only (<= NPAST)

  const f32x4* K4 = (const f32x4*)Kp + (size_t)bh * NPAST * 64;
  const f32x4* V4 = (const f32x4*)Vp + (size_t)bh * NPAST * 64;
  const float4 qv = ((const float4*)qb)[bh * 64 + lane];
  const float* mrow = mask + b * STOT;

  float m = -3.0e38f, l = 0.f;
  float4 ctx = make_float4(0.f, 0.f, 0.f, 0.f);

  int j = start + wid;
  f32x4 kk = __builtin_nontemporal_load(K4 + (size_t)j * 64 + lane);
  f32x4 vv = __builtin_nontemporal_load(V4 + (size_t)j * 64 + lane);
  float mk = mrow[j];

  while (j < end) {
    const int jn = j + 4;
    f32x4 kk2, vv2;
    float mk2;
    if (jn < end) {                          // wave-uniform; prefetch next
      kk2 = __builtin_nontemporal_load(K4 + (size_t)jn * 64 + lane);
      vv2 = __builtin_nontemporal_load(V4 + (size_t)jn * 64 + lane);
      mk2 = mrow[jn];
    }
    float s = dot4v(kk, qv);
#pragma unroll
    for (int off = 32; off > 0; off >>= 1) s += __shfl_xor(s, off, 64);
    s = s * 0.0625f + mk;                    // scale = 1/sqrt(256)
    const float mn = fmaxf(m, s);
    const float corr = __expf(m - mn);
    const float p = __expf(s - mn);
    l = l * corr + p;
    ctx.x = fmaf(ctx.x, corr, p * vv.x);
    ctx.y = fmaf(ctx.y, corr, p * vv.y);
    ctx.z = fmaf(ctx.z, corr, p * vv.z);
    ctx.w = fmaf(ctx.w, corr, p * vv.w);
    m = mn;
    j = jn; kk = kk2; vv = vv2; mk = mk2;
  }

  // new token's key (index NPAST): handled once, by last split / wave 0
  if (split == NSPLIT - 1 && wid == 0) {
    const float4 kn = ((const float4*)kb)[bh * 64 + lane];
    const float4 vn = ((const float4*)vb)[bh * 64 + lane];
    float s = dot4(kn, qv);
#pragma unroll
    for (int off = 32; off > 0; off >>= 1) s += __shfl_xor(s, off, 64);
    s = s * 0.0625f + mrow[NPAST];
    const float mn = fmaxf(m, s);
    const float corr = __expf(m - mn);
    const float p = __expf(s - mn);
    l = l * corr + p;
    ctx.x = fmaf(ctx.x, corr, p * vn.x);
    ctx.y = fmaf(ctx.y, corr, p * vn.y);
    ctx.z = fmaf(ctx.z, corr, p * vn.z);
    ctx.w = fmaf(ctx.w, corr, p * vn.w);
    m = mn;
  }

  // combine the block's 4 waves
  __shared__ float sm[4], sl[4];
  __shared__ float4 sctx[4][64];
  if (lane == 0) { sm[wid] = m; sl[wid] = l; }
  sctx[wid][lane] = ctx;
  __syncthreads();

  const float M = fmaxf(fmaxf(sm[0], sm[1]), fmaxf(sm[2], sm[3]));
  const int e = threadIdx.x;                  // 0..255
  const float* sc = (const float*)sctx;       // [4][256]
  float accv = 0.f;
#pragma unroll
  for (int w = 0; w < 4; ++w) accv += sc[w * 256 + e] * __expf(sm[w] - M);
  pc[(size_t)blk * 256 + e] = accv;
  if (threadIdx.x == 0) {
    float L = 0.f;
#pragma unroll
    for (int w = 0; w < 4; ++w) L += sl[w] * __expf(sm[w] - M);
    pm[blk] = M;
    pl[blk] = L;
  }
}

// ---------------- kernel 3: combine splits -> ctx_full ------------------------
__global__ __launch_bounds__(256) void k_comb(const float* __restrict__ pm,
                                              const float* __restrict__ pl,
                                              const float* __restrict__ pc,
                                              float* __restrict__ ctxf) {
  const int bh = blockIdx.x;
  const int e  = threadIdx.x;
  float M = -3.0e38f;
  for (int s = 0; s < NSPLIT; ++s) M = fmaxf(M, pm[bh * NSPLIT + s]);
  float L = 0.f, acc = 0.f;
  for (int s = 0; s < NSPLIT; ++s) {
    const float c = __expf(pm[bh * NSPLIT + s] - M);
    L   += pl[bh * NSPLIT + s] * c;
    acc += pc[((size_t)bh * NSPLIT + s) * 256 + e] * c;
  }
  ctxf[bh * 256 + e] = acc / L;   // [b][h*256+e] layout == transpose+reshape
}

// ---------------- kernel 4: output projection GEMV, 2 rows/wave --------------
__global__ __launch_bounds__(256) void k_out(const float* __restrict__ ctxf,
                                             const float* __restrict__ Wo,
                                             float* __restrict__ out) {
  const int lane = threadIdx.x & 63;
  const int wid  = threadIdx.x >> 6;
  const int task = blockIdx.x * 4 + wid;      // 0..2047
  const int r    = task << 1;                 // 2 rows per wave
  const float4* W4 = (const float4*)(Wo + (size_t)r * DM);
  const float4* x4 = (const float4*)ctxf;

  float a0[8], a1[8];
#pragma unroll
  for (int b = 0; b < 8; ++b) a0[b] = a1[b] = 0.f;

  for (int it = 0; it < 16; ++it) {
    const int c4 = it * 64 + lane;
    const float4 w0 = W4[c4];
    const float4 w1 = W4[1024 + c4];
#pragma unroll
    for (int b = 0; b < 8; ++b) {
      const float4 hv = x4[b * 1024 + c4];
      a0[b] += dot4(w0, hv);
      a1[b] += dot4(w1, hv);
    }
  }
#pragma unroll
  for (int off = 32; off > 0; off >>= 1) {
#pragma unroll
    for (int b = 0; b < 8; ++b) {
      a0[b] += __shfl_xor(a0[b], off, 64);
      a1[b] += __shfl_xor(a1[b], off, 64);
    }
  }
#pragma unroll
  for (int b = 0; b < 8; ++b) {
    if (lane == b) {
      out[b * DM + r + 0] = a0[b];
      out[b * DM + r + 1] = a1[b];
    }
  }
}

extern "C" void kernel_launch(void* const* d_in, const int* in_sizes, int n_in,
                              void* d_out, int out_size, void* d_ws, size_t ws_size,
                              hipStream_t stream) {
  const float* hid  = (const float*)d_in[0];   // [8,1,4096]
  const float* Kp   = (const float*)d_in[1];   // [8,16,4096,256]
  const float* Vp   = (const float*)d_in[2];   // [8,16,4096,256]
  const float* mask = (const float*)d_in[3];   // [8,1,1,4097]
  const int*   pos  = (const int*)d_in[4];     // [8,1] (int32 on device)
  const float* Wq   = (const float*)d_in[5];   // [4096,4096]
  const float* Wk   = (const float*)d_in[6];
  const float* Wv   = (const float*)d_in[7];
  const float* Wo   = (const float*)d_in[8];

  float* ws   = (float*)d_ws;
  float* qb   = ws;                 // 32768  (B*DM)
  float* kb   = ws + 32768;         // 32768
  float* vb   = ws + 65536;         // 32768
  float* ctxf = ws + 98304;         // 32768
  float* pm   = ws + 131072;        // 1024   (B*H*NSPLIT)
  float* pl   = ws + 135168;        // 1024
  float* pc   = ws + 139264;        // 262144 (B*H*NSPLIT*256)

  k_qkv <<<768, 256, 0, stream>>>(hid, Wq, Wk, Wv, pos, qb, kb, vb);
  k_attn<<<NB * NH * NSPLIT, 256, 0, stream>>>(qb, kb, vb, Kp, Vp, mask, pm, pl, pc);
  k_comb<<<NB * NH, 256, 0, stream>>>(pm, pl, pc, ctxf);
  k_out <<<512, 256, 0, stream>>>(ctxf, Wo, (float*)d_out);
}